// Round 10
// baseline (304.993 us; speedup 1.0000x reference)
//
#include <hip/hip_runtime.h>

#define N_NODES 50000
#define N_EDGES 1600000
#define HD 64    // H*D
#define NH 8     // heads
#define NBKT 196 // dst buckets (dst >> 8)
#define EPB 8192 // edges per block in binning passes
#define GB1 196  // ceil(N_EDGES / EPB)
#define SCAN_M (NBKT * GB1)   // 38416
#define NB2 151               // ceil(SCAN_M / 256)
#define DCAP 8960             // pass-D LDS edge capacity (mean 8192, +8.5 sigma)
#define SEGB 2048             // 256 dst-low bins x 8 src segments
#define GBN 196               // ceil(N_NODES / 256) node blocks for gemm

__device__ inline int wave_incl_scan(int v, int lane) {
#pragma unroll
    for (int o = 1; o < 64; o <<= 1) {
        int t = __shfl_up(v, o);
        if (lane >= o) v += t;
    }
    return v;
}

// ------------------------------------------------- GEMM + attention logits
// PROVEN config: thread = node, 16 output features (= 2 complete heads),
// 4 y-blocks. x re-reads are L3-absorbed; narrow tile keeps VGPR/SGPR
// pressure low -> deep load pipelining. 32/64-wide measured SLOWER.
// (Only used for layer 0 now; layers 1-3 GEMMs are fused into aggemm.)
template <int F>
__device__ __forceinline__ void gemm_body16(
    int bx, int by, int t,
    const float* __restrict__ x, const float* __restrict__ W,
    const float* __restrict__ att,
    _Float16* __restrict__ h, float* __restrict__ es, float* __restrict__ ed) {
    int n = bx * 256 + t;
    int f0 = by * 16;
    int nc = (n < N_NODES) ? n : (N_NODES - 1);
    const float4* xrow = (const float4*)x + (size_t)nc * (F / 4);
    float acc[16];
#pragma unroll
    for (int i = 0; i < 16; i++) acc[i] = 0.f;
#pragma unroll 4
    for (int kk = 0; kk < F / 4; kk++) {
        float4 xv = xrow[kk];
        const float* Wk = W + (kk * 4) * 64 + f0;  // wave-uniform base
#pragma unroll
        for (int i = 0; i < 16; i++)
            acc[i] += xv.x * Wk[i] + xv.y * Wk[64 + i] +
                      xv.z * Wk[128 + i] + xv.w * Wk[192 + i];
    }
    if (n >= N_NODES) return;

    float s0 = 0.f, s1 = 0.f, d0 = 0.f, d1 = 0.f;
#pragma unroll
    for (int i = 0; i < 8; i++) {
        s0 += acc[i] * att[f0 + i];
        d0 += acc[i] * att[64 + f0 + i];
    }
#pragma unroll
    for (int i = 8; i < 16; i++) {
        s1 += acc[i] * att[f0 + i];
        d1 += acc[i] * att[64 + f0 + i];
    }
    int hh = f0 >> 3;
    es[n * NH + hh] = s0; es[n * NH + hh + 1] = s1;
    ed[n * NH + hh] = d0; ed[n * NH + hh + 1] = d1;

    union { _Float16 hf[16]; uint4 u[2]; } cv;
#pragma unroll
    for (int i = 0; i < 16; i++) cv.hf[i] = (_Float16)acc[i];
    uint4* hp = (uint4*)(h + (size_t)n * HD + f0);
    hp[0] = cv.u[0];
    hp[1] = cv.u[1];
}

// ---------------------------------------------------- CSR build (no global atomics)
// Fused: grid (GBN, 5). y<4 -> gemm layer0 y-block (hides histA); y==4 ->
// dst histogram block (GB1 == GBN == 196).
__global__ __launch_bounds__(256) void histA_gemm_kernel(
    const int* __restrict__ dst, int* __restrict__ offs,
    const float* __restrict__ x, const float* __restrict__ W,
    const float* __restrict__ att,
    _Float16* __restrict__ h, float* __restrict__ es, float* __restrict__ ed) {
    if (blockIdx.y < 4) {
        gemm_body16<128>(blockIdx.x, blockIdx.y, threadIdx.x, x, W, att, h, es, ed);
        return;
    }
    int bb = blockIdx.x;
    __shared__ int hist[NBKT];
    int t = threadIdx.x;
    if (t < NBKT) hist[t] = 0;
    __syncthreads();
    int base = bb * EPB;
#pragma unroll
    for (int k = 0; k < EPB / 256; k++) {
        int e = base + k * 256 + t;
        if (e < N_EDGES) atomicAdd(&hist[dst[e] >> 8], 1);
    }
    __syncthreads();
    if (t < NBKT) offs[t * GB1 + bb] = hist[t];
}

__global__ __launch_bounds__(256) void scanB1_kernel(int* __restrict__ offs,
                                                     int* __restrict__ part2) {
    __shared__ int wsum[4];
    int t = threadIdx.x, lane = t & 63, wv = t >> 6;
    int i = blockIdx.x * 256 + t;
    int v = (i < SCAN_M) ? offs[i] : 0;
    int inc = wave_incl_scan(v, lane);
    if (lane == 63) wsum[wv] = inc;
    __syncthreads();
    if (t == 0) {
        int a = 0;
        for (int k = 0; k < 4; k++) { int x = wsum[k]; wsum[k] = a; a += x; }
    }
    __syncthreads();
    int excl = wsum[wv] + inc - v;
    if (i < SCAN_M) offs[i] = excl;
    if (t == 255) part2[blockIdx.x] = wsum[wv] + inc;
}

// scanB2 folded into consumers: each block exclusive-scans part2 (151 ints) in LDS.
__global__ __launch_bounds__(256) void scatC_kernel(const int* __restrict__ src,
                                                    const int* __restrict__ dst,
                                                    const int* __restrict__ offs,
                                                    const int* __restrict__ part2,
                                                    unsigned* __restrict__ ebuf) {
    __shared__ int cur[NBKT];
    __shared__ int base_s[NBKT];
    __shared__ int p2s[256];
    __shared__ int p2w[4];
    int t = threadIdx.x, lane = t & 63, wv = t >> 6;
    int v = (t < NB2) ? part2[t] : 0;
    int inc = wave_incl_scan(v, lane);
    if (lane == 63) p2w[wv] = inc;
    __syncthreads();
    if (t == 0) {
        int a = 0;
        for (int k = 0; k < 4; k++) { int x = p2w[k]; p2w[k] = a; a += x; }
    }
    __syncthreads();
    p2s[t] = p2w[wv] + inc - v;
    if (t < NBKT) cur[t] = 0;
    __syncthreads();
    if (t < NBKT) {
        int f = t * GB1 + blockIdx.x;
        base_s[t] = offs[f] + p2s[f >> 8];
    }
    __syncthreads();
    int base = blockIdx.x * EPB;
#pragma unroll
    for (int k = 0; k < EPB / 256; k++) {
        int e = base + k * 256 + t;
        if (e < N_EDGES) {
            int d = dst[e];
            int b = d >> 8;
            int r = atomicAdd(&cur[b], 1);
            ebuf[base_s[b] + r] = (unsigned)src[e] | ((unsigned)(d & 255) << 16);
        }
    }
}

__global__ __launch_bounds__(512) void csrD_kernel(const int* __restrict__ offs,
                                                   const int* __restrict__ part2,
                                                   const unsigned* __restrict__ ebuf,
                                                   int* __restrict__ rowptr,
                                                   unsigned short* __restrict__ csr) {
    __shared__ unsigned eb[DCAP];
    __shared__ int hist[SEGB];
    __shared__ int wsum[8];
    __shared__ int p2s[512];
    int b = blockIdx.x, t = threadIdx.x;
    int lane = t & 63, wv = t >> 6;
    {   // in-block exclusive scan of part2 (replaces scanB2 dispatch)
        int v = (t < NB2) ? part2[t] : 0;
        int inc = wave_incl_scan(v, lane);
        if (lane == 63) wsum[wv] = inc;
        __syncthreads();
        if (t == 0) {
            int a = 0;
            for (int k = 0; k < 8; k++) { int x = wsum[k]; wsum[k] = a; a += x; }
        }
        __syncthreads();
        p2s[t] = wsum[wv] + inc - v;
        __syncthreads();
    }
    int f0 = b * GB1;
    int base = offs[f0] + p2s[f0 >> 8];
    int nxt;
    if (b == NBKT - 1) nxt = N_EDGES;
    else { int f1 = (b + 1) * GB1; nxt = offs[f1] + p2s[f1 >> 8]; }
    int nb = nxt - base;
    if (nb > DCAP) nb = DCAP;  // statistically impossible; guards LDS OOB
    for (int i = t; i < SEGB; i += 512) hist[i] = 0;
    __syncthreads();
    for (int i = t; i < nb; i += 512) {
        unsigned v = ebuf[base + i];
        eb[i] = v;
        int bin = (int)((v >> 16) << 3) | (int)((v & 0xFFFFu) >> 13);
        atomicAdd(&hist[bin], 1);
    }
    __syncthreads();
    int b0 = t << 2;
    int loc0 = hist[b0], loc1 = hist[b0 + 1], loc2 = hist[b0 + 2], loc3 = hist[b0 + 3];
    int s = loc0 + loc1 + loc2 + loc3;
    int inc = wave_incl_scan(s, lane);
    if (lane == 63) wsum[wv] = inc;
    __syncthreads();
    if (t == 0) {
        int a = 0;
        for (int k = 0; k < 8; k++) { int x = wsum[k]; wsum[k] = a; a += x; }
    }
    __syncthreads();
    int run = wsum[wv] + inc - s;
    hist[b0] = run; run += loc0;
    hist[b0 + 1] = run; run += loc1;
    hist[b0 + 2] = run; run += loc2;
    hist[b0 + 3] = run;
    __syncthreads();
    if (t < 256) {
        int node = b * 256 + t;
        if (node < N_NODES) rowptr[node] = base + hist[t << 3];
    }
    if (b == 0 && t == 0) rowptr[N_NODES] = N_EDGES;
    __syncthreads();
    for (int i = t; i < nb; i += 512) {
        unsigned v = eb[i];
        int bin = (int)((v >> 16) << 3) | (int)((v & 0xFFFFu) >> 13);
        int r = atomicAdd(&hist[bin], 1);
        csr[base + r] = (unsigned short)(v & 0xFFFFu);
    }
}

// ---------------------------------------------- fused f16*f32+f32 accumulate
// v_fma_mix_f32: D.f32 = f16(half of S0) * S1.f32 + S2.f32 -- replaces the
// cvt_f32_f16 + fma pair (bitwise-identical arithmetic, half the VALU ops).
// NOTE (r7/r8 compile fails): asm operands must be plain scalar locals, and
// macro parameter must NOT be named `w` (token-substitutes into `.w`!).
__device__ __forceinline__ void fmamix2(float& alo, float& ahi, unsigned dw,
                                        float wgt) {
    asm("v_fma_mix_f32 %0, %2, %3, %0 op_sel_hi:[1,0,0]"
        : "=v"(alo) : "0"(alo), "v"(dw), "v"(wgt));
    asm("v_fma_mix_f32 %0, %2, %3, %0 op_sel:[1,0,0] op_sel_hi:[1,0,0]"
        : "=v"(ahi) : "0"(ahi), "v"(dw), "v"(wgt));
}

#define EDGE_ACC(hv, wgt) do {                                               \
    unsigned _d0 = (hv).x, _d1 = (hv).y, _d2 = (hv).z, _d3 = (hv).w;         \
    float _w = (wgt);                                                        \
    fmamix2(acc[0], acc[1], _d0, _w);                                        \
    fmamix2(acc[2], acc[3], _d1, _w);                                        \
    fmamix2(acc[4], acc[5], _d2, _w);                                        \
    fmamix2(acc[6], acc[7], _d3, _w);                                        \
} while (0)

// ---------------------------------------------- agg loop (shared by both kernels)
// SPLIT-WAVE: each HALF-WAVE (32 lanes = 4 edge slots x 8 heads) owns one
// node with its OWN exact trip count. 32-edge bulk iterations: 8 csr + 8
// h-gather + 8 es loads hoisted before any compute -> 2x in-flight lines
// per wave, half the dependent csr->gather round-trips (agg is gather-
// LATENCY bound: ~2.5x above its ~12 us L2/L3 BW floor). Group A/B compute
// preserves the exact per-lane edge order + ssum pairing of two consecutive
// 16-edge iterations -> bitwise-identical result to round 9.
#define AGG_LOOP()                                                          \
    int beg = rowptr[n], end = rowptr[n + 1];                               \
    float edn = ed_in[n * NH + o];                                          \
    int last = (end > beg) ? (end - 1) : 0;                                 \
    float acc[8] = {0.f, 0.f, 0.f, 0.f, 0.f, 0.f, 0.f, 0.f};                \
    float ssum = 0.f;                                                       \
    int j = beg;                                                            \
    for (; j + 32 <= end; j += 32) {                                        \
        int s0 = csr[j + g];                                                \
        int s1 = csr[j + 4 + g];                                            \
        int s2 = csr[j + 8 + g];                                            \
        int s3 = csr[j + 12 + g];                                           \
        int s4 = csr[j + 16 + g];                                           \
        int s5 = csr[j + 20 + g];                                           \
        int s6 = csr[j + 24 + g];                                           \
        int s7 = csr[j + 28 + g];                                           \
        uint4 hv0 = h8[s0 * 8 + o];                                         \
        uint4 hv1 = h8[s1 * 8 + o];                                         \
        uint4 hv2 = h8[s2 * 8 + o];                                         \
        uint4 hv3 = h8[s3 * 8 + o];                                         \
        uint4 hv4 = h8[s4 * 8 + o];                                         \
        uint4 hv5 = h8[s5 * 8 + o];                                         \
        uint4 hv6 = h8[s6 * 8 + o];                                         \
        uint4 hv7 = h8[s7 * 8 + o];                                         \
        float ev0 = es_in[s0 * NH + o];                                     \
        float ev1 = es_in[s1 * NH + o];                                     \
        float ev2 = es_in[s2 * NH + o];                                     \
        float ev3 = es_in[s3 * NH + o];                                     \
        float ev4 = es_in[s4 * NH + o];                                     \
        float ev5 = es_in[s5 * NH + o];                                     \
        float ev6 = es_in[s6 * NH + o];                                     \
        float ev7 = es_in[s7 * NH + o];                                     \
        float e0 = ev0 + edn; e0 = (e0 > 0.f) ? e0 : 0.2f * e0;             \
        float e1 = ev1 + edn; e1 = (e1 > 0.f) ? e1 : 0.2f * e1;             \
        float e2 = ev2 + edn; e2 = (e2 > 0.f) ? e2 : 0.2f * e2;             \
        float e3 = ev3 + edn; e3 = (e3 > 0.f) ? e3 : 0.2f * e3;             \
        float w0 = __expf(e0), w1 = __expf(e1);                             \
        float w2 = __expf(e2), w3 = __expf(e3);                             \
        EDGE_ACC(hv0, w0);                                                  \
        EDGE_ACC(hv1, w1);                                                  \
        EDGE_ACC(hv2, w2);                                                  \
        EDGE_ACC(hv3, w3);                                                  \
        ssum += w0 + w1;                                                    \
        ssum += w2 + w3;                                                    \
        float e4 = ev4 + edn; e4 = (e4 > 0.f) ? e4 : 0.2f * e4;             \
        float e5 = ev5 + edn; e5 = (e5 > 0.f) ? e5 : 0.2f * e5;             \
        float e6 = ev6 + edn; e6 = (e6 > 0.f) ? e6 : 0.2f * e6;             \
        float e7 = ev7 + edn; e7 = (e7 > 0.f) ? e7 : 0.2f * e7;             \
        float w4 = __expf(e4), w5 = __expf(e5);                             \
        float w6 = __expf(e6), w7 = __expf(e7);                             \
        EDGE_ACC(hv4, w4);                                                  \
        EDGE_ACC(hv5, w5);                                                  \
        EDGE_ACC(hv6, w6);                                                  \
        EDGE_ACC(hv7, w7);                                                  \
        ssum += w4 + w5;                                                    \
        ssum += w6 + w7;                                                    \
    }                                                                       \
    for (; j + 16 <= end; j += 16) {                                        \
        int s0 = csr[j + g];                                                \
        int s1 = csr[j + 4 + g];                                            \
        int s2 = csr[j + 8 + g];                                            \
        int s3 = csr[j + 12 + g];                                           \
        uint4 hv0 = h8[s0 * 8 + o];                                         \
        uint4 hv1 = h8[s1 * 8 + o];                                         \
        uint4 hv2 = h8[s2 * 8 + o];                                         \
        uint4 hv3 = h8[s3 * 8 + o];                                         \
        float ev0 = es_in[s0 * NH + o];                                     \
        float ev1 = es_in[s1 * NH + o];                                     \
        float ev2 = es_in[s2 * NH + o];                                     \
        float ev3 = es_in[s3 * NH + o];                                     \
        float e0 = ev0 + edn; e0 = (e0 > 0.f) ? e0 : 0.2f * e0;             \
        float e1 = ev1 + edn; e1 = (e1 > 0.f) ? e1 : 0.2f * e1;             \
        float e2 = ev2 + edn; e2 = (e2 > 0.f) ? e2 : 0.2f * e2;             \
        float e3 = ev3 + edn; e3 = (e3 > 0.f) ? e3 : 0.2f * e3;             \
        float w0 = __expf(e0), w1 = __expf(e1);                             \
        float w2 = __expf(e2), w3 = __expf(e3);                             \
        EDGE_ACC(hv0, w0);                                                  \
        EDGE_ACC(hv1, w1);                                                  \
        EDGE_ACC(hv2, w2);                                                  \
        EDGE_ACC(hv3, w3);                                                  \
        ssum += w0 + w1;                                                    \
        ssum += w2 + w3;                                                    \
    }                                                                       \
    if (j < end) {                                                          \
        int i0 = j + g, i1 = j + 4 + g, i2 = j + 8 + g, i3 = j + 12 + g;    \
        int s0 = csr[(i0 < end) ? i0 : last];                               \
        int s1 = csr[(i1 < end) ? i1 : last];                               \
        int s2 = csr[(i2 < end) ? i2 : last];                               \
        int s3 = csr[(i3 < end) ? i3 : last];                               \
        uint4 hv0 = h8[s0 * 8 + o];                                         \
        uint4 hv1 = h8[s1 * 8 + o];                                         \
        uint4 hv2 = h8[s2 * 8 + o];                                         \
        uint4 hv3 = h8[s3 * 8 + o];                                         \
        float ev0 = es_in[s0 * NH + o];                                     \
        float ev1 = es_in[s1 * NH + o];                                     \
        float ev2 = es_in[s2 * NH + o];                                     \
        float ev3 = es_in[s3 * NH + o];                                     \
        float e0 = ev0 + edn; e0 = (e0 > 0.f) ? e0 : 0.2f * e0;             \
        float e1 = ev1 + edn; e1 = (e1 > 0.f) ? e1 : 0.2f * e1;             \
        float e2 = ev2 + edn; e2 = (e2 > 0.f) ? e2 : 0.2f * e2;             \
        float e3 = ev3 + edn; e3 = (e3 > 0.f) ? e3 : 0.2f * e3;             \
        float w0 = (i0 < end) ? __expf(e0) : 0.f;                           \
        float w1 = (i1 < end) ? __expf(e1) : 0.f;                           \
        float w2 = (i2 < end) ? __expf(e2) : 0.f;                           \
        float w3 = (i3 < end) ? __expf(e3) : 0.f;                           \
        EDGE_ACC(hv0, w0);                                                  \
        EDGE_ACC(hv1, w1);                                                  \
        EDGE_ACC(hv2, w2);                                                  \
        EDGE_ACC(hv3, w3);                                                  \
        ssum += w0 + w1;                                                    \
        ssum += w2 + w3;                                                    \
    }                                                                       \
    _Pragma("unroll")                                                       \
    for (int i = 0; i < 8; i++) {                                           \
        acc[i] += __shfl_xor(acc[i], 8);                                    \
        acc[i] += __shfl_xor(acc[i], 16);                                   \
    }                                                                       \
    ssum += __shfl_xor(ssum, 8);                                            \
    ssum += __shfl_xor(ssum, 16);

// ------------------------------------------------------------- aggregation
// Final layer: plain agg -> d_out, no ELU.
__global__ __launch_bounds__(256) void agg_kernel(
    const uint4* __restrict__ h8, const float* __restrict__ es_in,
    const float* __restrict__ ed_in, const int* __restrict__ rowptr,
    const unsigned short* __restrict__ csr, const float4* __restrict__ b4,
    float4* __restrict__ out4, int apply_elu) {
    int t = threadIdx.x;
    int wv = t >> 6, L = t & 63;
    int n = blockIdx.x * 8 + wv * 2 + (L >> 5);
    int g = (L >> 3) & 3, o = L & 7;
    AGG_LOOP()

    if (g == 0) {
        float inv = 1.f / (ssum + 1e-16f);
        float4 bv0 = b4[2 * o], bv1 = b4[2 * o + 1];
        float4 r0, r1;
        r0.x = acc[0] * inv + bv0.x; r0.y = acc[1] * inv + bv0.y;
        r0.z = acc[2] * inv + bv0.z; r0.w = acc[3] * inv + bv0.w;
        r1.x = acc[4] * inv + bv1.x; r1.y = acc[5] * inv + bv1.y;
        r1.z = acc[6] * inv + bv1.z; r1.w = acc[7] * inv + bv1.w;
        if (apply_elu) {
            r0.x = (r0.x > 0.f) ? r0.x : (__expf(r0.x) - 1.f);
            r0.y = (r0.y > 0.f) ? r0.y : (__expf(r0.y) - 1.f);
            r0.z = (r0.z > 0.f) ? r0.z : (__expf(r0.z) - 1.f);
            r0.w = (r0.w > 0.f) ? r0.w : (__expf(r0.w) - 1.f);
            r1.x = (r1.x > 0.f) ? r1.x : (__expf(r1.x) - 1.f);
            r1.y = (r1.y > 0.f) ? r1.y : (__expf(r1.y) - 1.f);
            r1.z = (r1.z > 0.f) ? r1.z : (__expf(r1.z) - 1.f);
            r1.w = (r1.w > 0.f) ? r1.w : (__expf(r1.w) - 1.f);
        }
        out4[n * 16 + 2 * o] = r0;
        out4[n * 16 + 2 * o + 1] = r1;
    }
}

// ----------------------------------------- aggregation + NEXT-LAYER GEMM fused
// Layers 0-2: agg output row (bias+ELU) is NODE-LOCAL input to the next
// layer's GEMM -> keep it in LDS, run the 64x64 GEMM as an epilogue in the
// same half-wave (lane = 2 features), write h/es/ed for the next layer.
// W_next staged per block in pair-interleaved LDS layout wTp[li*132+k*2+c]
// = W[k][2*li+c] (stride 132 floats: 16B-aligned b128 rows, <=4-way banks).
__global__ __launch_bounds__(256) void aggemm_kernel(
    const uint4* __restrict__ h8, const float* __restrict__ es_in,
    const float* __restrict__ ed_in, const int* __restrict__ rowptr,
    const unsigned short* __restrict__ csr, const float4* __restrict__ b4,
    const float* __restrict__ Wn, const float* __restrict__ attn,
    _Float16* __restrict__ h_out, float* __restrict__ es_out,
    float* __restrict__ ed_out) {
    __shared__ alignas(16) float wTp[32 * 132];
    __shared__ alignas(16) float outs[8][64];
    int t = threadIdx.x;
    {   // stage W_next (16 KB) -> LDS; issues early, covered by agg latency
        const float4* W4 = (const float4*)Wn;
#pragma unroll
        for (int q = 0; q < 4; q++) {
            int idx4 = q * 256 + t;      // 1024 float4 = 4096 floats
            float4 wv4 = W4[idx4];
            int base = idx4 << 2;
            int k = base >> 6, fb = base & 63;   // fb multiple of 4
            float2* p0 = (float2*)&wTp[(fb >> 1) * 132 + k * 2];
            float2* p1 = (float2*)&wTp[((fb >> 1) + 1) * 132 + k * 2];
            p0->x = wv4.x; p0->y = wv4.y;
            p1->x = wv4.z; p1->y = wv4.w;
        }
    }
    int wv = t >> 6, L = t & 63;
    int slot = wv * 2 + (L >> 5);
    int n = blockIdx.x * 8 + slot;
    int g = (L >> 3) & 3, o = L & 7;
    AGG_LOOP()

    if (g == 0) {   // bias + ELU (always: intermediate layers), row -> LDS
        float inv = 1.f / (ssum + 1e-16f);
        float4 bv0 = b4[2 * o], bv1 = b4[2 * o + 1];
        float4 r0, r1;
        r0.x = acc[0] * inv + bv0.x; r0.y = acc[1] * inv + bv0.y;
        r0.z = acc[2] * inv + bv0.z; r0.w = acc[3] * inv + bv0.w;
        r1.x = acc[4] * inv + bv1.x; r1.y = acc[5] * inv + bv1.y;
        r1.z = acc[6] * inv + bv1.z; r1.w = acc[7] * inv + bv1.w;
        r0.x = (r0.x > 0.f) ? r0.x : (__expf(r0.x) - 1.f);
        r0.y = (r0.y > 0.f) ? r0.y : (__expf(r0.y) - 1.f);
        r0.z = (r0.z > 0.f) ? r0.z : (__expf(r0.z) - 1.f);
        r0.w = (r0.w > 0.f) ? r0.w : (__expf(r0.w) - 1.f);
        r1.x = (r1.x > 0.f) ? r1.x : (__expf(r1.x) - 1.f);
        r1.y = (r1.y > 0.f) ? r1.y : (__expf(r1.y) - 1.f);
        r1.z = (r1.z > 0.f) ? r1.z : (__expf(r1.z) - 1.f);
        r1.w = (r1.w > 0.f) ? r1.w : (__expf(r1.w) - 1.f);
        float4* os = (float4*)&outs[slot][0];
        os[2 * o] = r0;
        os[2 * o + 1] = r1;
    }
    __syncthreads();

    // epilogue GEMM: lane covers features f0, f0+1 of the next layer
    int li = L & 31;
    int f0 = li << 1;
    const float* wrow = &wTp[li * 132];
    float h0 = 0.f, h1 = 0.f;
#pragma unroll
    for (int k4 = 0; k4 < 64; k4 += 4) {
        float4 ov = *(const float4*)&outs[slot][k4];       // broadcast/half
        float4 wa = *(const float4*)&wrow[k4 * 2];         // k4,k4+1 pairs
        float4 wb = *(const float4*)&wrow[k4 * 2 + 4];     // k4+2,k4+3 pairs
        h0 += ov.x * wa.x + ov.y * wa.z + ov.z * wb.x + ov.w * wb.z;
        h1 += ov.x * wa.y + ov.y * wa.w + ov.z * wb.y + ov.w * wb.w;
    }
    // attention logits for next layer (4-lane tree per head)
    float sa = h0 * attn[f0] + h1 * attn[f0 + 1];
    float da = h0 * attn[64 + f0] + h1 * attn[64 + f0 + 1];
    sa += __shfl_xor(sa, 1); sa += __shfl_xor(sa, 2);
    da += __shfl_xor(da, 1); da += __shfl_xor(da, 2);
    if ((li & 3) == 0) {
        int hh = li >> 2;
        es_out[n * NH + hh] = sa;
        ed_out[n * NH + hh] = da;
    }
    union { _Float16 hf[2]; unsigned u; } cv;
    cv.hf[0] = (_Float16)h0;
    cv.hf[1] = (_Float16)h1;
    *(unsigned*)(h_out + (size_t)n * HD + f0) = cv.u;
}

// ---------------------------------------------------------------- launcher
extern "C" void kernel_launch(void* const* d_in, const int* in_sizes, int n_in,
                              void* d_out, int out_size, void* d_ws, size_t ws_size,
                              hipStream_t stream) {
    const float* x   = (const float*)d_in[0];
    const int*   ei  = (const int*)d_in[1];
    const int*   src = ei;
    const int*   dst = ei + N_EDGES;
    const float* W[4]   = {(const float*)d_in[2], (const float*)d_in[5],
                           (const float*)d_in[8], (const float*)d_in[11]};
    const float* att[4] = {(const float*)d_in[3], (const float*)d_in[6],
                           (const float*)d_in[9], (const float*)d_in[12]};
    const float* bb[4]  = {(const float*)d_in[4], (const float*)d_in[7],
                           (const float*)d_in[10], (const float*)d_in[13]};

    char* wsb = (char*)d_ws;
    size_t off = 0;
    auto alloc = [&](size_t bytes) -> void* {
        size_t a = (off + 255) & ~(size_t)255;
        off = a + bytes;
        return (void*)(wsb + a);
    };
    int*            offs   = (int*)alloc((size_t)SCAN_M * 4);
    int*            part2  = (int*)alloc((size_t)NB2 * 4);
    unsigned*       ebuf   = (unsigned*)alloc((size_t)N_EDGES * 4);
    int*            rowptr = (int*)alloc((size_t)(N_NODES + 1) * 4);
    unsigned short* csr    = (unsigned short*)alloc((size_t)N_EDGES * 2);
    _Float16*       h_a    = (_Float16*)alloc((size_t)N_NODES * HD * 2);
    float*          es_a   = (float*)alloc((size_t)N_NODES * NH * 4);
    float*          ed_a   = (float*)alloc((size_t)N_NODES * NH * 4);
    _Float16*       h_b    = (_Float16*)alloc((size_t)N_NODES * HD * 2);
    float*          es_b   = (float*)alloc((size_t)N_NODES * NH * 4);
    float*          ed_b   = (float*)alloc((size_t)N_NODES * NH * 4);

    const int GA = N_NODES / 8;  // 6250 blocks, 8 nodes per block
    const dim3 GF(GBN, 5);       // y<4: gemm layer0, y==4: histA

    // CSR build + layer-0 GEMM fused (independent work overlapped)
    histA_gemm_kernel<<<GF, 256, 0, stream>>>(dst, offs, x, W[0], att[0],
                                              h_a, es_a, ed_a);
    scanB1_kernel<<<NB2, 256, 0, stream>>>(offs, part2);
    scatC_kernel<<<GB1, 256, 0, stream>>>(src, dst, offs, part2, ebuf);
    csrD_kernel<<<NBKT, 512, 0, stream>>>(offs, part2, ebuf, rowptr, csr);

    // layers 0-2: agg + fused next-layer GEMM (double-buffered h/es/ed)
    aggemm_kernel<<<GA, 256, 0, stream>>>((const uint4*)h_a, es_a, ed_a,
                                          rowptr, csr, (const float4*)bb[0],
                                          W[1], att[1], h_b, es_b, ed_b);
    aggemm_kernel<<<GA, 256, 0, stream>>>((const uint4*)h_b, es_b, ed_b,
                                          rowptr, csr, (const float4*)bb[1],
                                          W[2], att[2], h_a, es_a, ed_a);
    aggemm_kernel<<<GA, 256, 0, stream>>>((const uint4*)h_a, es_a, ed_a,
                                          rowptr, csr, (const float4*)bb[2],
                                          W[3], att[3], h_b, es_b, ed_b);
    // final layer: plain agg -> d_out (no ELU)
    agg_kernel<<<GA, 256, 0, stream>>>((const uint4*)h_b, es_b, ed_b,
                                       rowptr, csr, (const float4*)bb[3],
                                       (float4*)d_out, 0);
}

// Round 12
// 289.775 us; speedup vs baseline: 1.0525x; 1.0525x over previous
//
#include <hip/hip_runtime.h>

#define N_NODES 50000
#define N_EDGES 1600000
#define HD 64    // H*D
#define NH 8     // heads
#define NBKT 196 // dst buckets (dst >> 8)
#define EPB 8192 // edges per block in binning passes
#define GB1 196  // ceil(N_EDGES / EPB)
#define SCAN_M (NBKT * GB1)   // 38416
#define NB2 151               // ceil(SCAN_M / 256)
#define DCAP 8960             // pass-D LDS edge capacity (mean 8192, +8.5 sigma)
#define SEGB 2048             // 256 dst-low bins x 8 src segments
#define GBN 196               // ceil(N_NODES / 256) node blocks for gemm

__device__ inline int wave_incl_scan(int v, int lane) {
#pragma unroll
    for (int o = 1; o < 64; o <<= 1) {
        int t = __shfl_up(v, o);
        if (lane >= o) v += t;
    }
    return v;
}

// ------------------------------------------------- GEMM + attention logits
// PROVEN config: thread = node, 16 output features (= 2 complete heads),
// 4 y-blocks. x re-reads are L3-absorbed; narrow tile keeps VGPR/SGPR
// pressure low -> deep load pipelining. 32/64-wide measured SLOWER.
// (Only used for layer 0 now; layers 1-3 GEMMs are fused into aggemm.)
template <int F>
__device__ __forceinline__ void gemm_body16(
    int bx, int by, int t,
    const float* __restrict__ x, const float* __restrict__ W,
    const float* __restrict__ att,
    _Float16* __restrict__ h, float* __restrict__ es, float* __restrict__ ed) {
    int n = bx * 256 + t;
    int f0 = by * 16;
    int nc = (n < N_NODES) ? n : (N_NODES - 1);
    const float4* xrow = (const float4*)x + (size_t)nc * (F / 4);
    float acc[16];
#pragma unroll
    for (int i = 0; i < 16; i++) acc[i] = 0.f;
#pragma unroll 4
    for (int kk = 0; kk < F / 4; kk++) {
        float4 xv = xrow[kk];
        const float* Wk = W + (kk * 4) * 64 + f0;  // wave-uniform base
#pragma unroll
        for (int i = 0; i < 16; i++)
            acc[i] += xv.x * Wk[i] + xv.y * Wk[64 + i] +
                      xv.z * Wk[128 + i] + xv.w * Wk[192 + i];
    }
    if (n >= N_NODES) return;

    float s0 = 0.f, s1 = 0.f, d0 = 0.f, d1 = 0.f;
#pragma unroll
    for (int i = 0; i < 8; i++) {
        s0 += acc[i] * att[f0 + i];
        d0 += acc[i] * att[64 + f0 + i];
    }
#pragma unroll
    for (int i = 8; i < 16; i++) {
        s1 += acc[i] * att[f0 + i];
        d1 += acc[i] * att[64 + f0 + i];
    }
    int hh = f0 >> 3;
    es[n * NH + hh] = s0; es[n * NH + hh + 1] = s1;
    ed[n * NH + hh] = d0; ed[n * NH + hh + 1] = d1;

    union { _Float16 hf[16]; uint4 u[2]; } cv;
#pragma unroll
    for (int i = 0; i < 16; i++) cv.hf[i] = (_Float16)acc[i];
    uint4* hp = (uint4*)(h + (size_t)n * HD + f0);
    hp[0] = cv.u[0];
    hp[1] = cv.u[1];
}

template <int F>
__global__ __launch_bounds__(256) void gemm_att_kernel(
    const float* __restrict__ x, const float* __restrict__ W,
    const float* __restrict__ att,
    _Float16* __restrict__ h, float* __restrict__ es, float* __restrict__ ed) {
    gemm_body16<F>(blockIdx.x, blockIdx.y, threadIdx.x, x, W, att, h, es, ed);
}

// ---------------------------------------------------- CSR build (no global atomics)
// Fused: grid (GBN, 5). y<4 -> gemm layer0 y-block (hides histA); y==4 ->
// dst histogram block (GB1 == GBN == 196).
__global__ __launch_bounds__(256) void histA_gemm_kernel(
    const int* __restrict__ dst, int* __restrict__ offs,
    const float* __restrict__ x, const float* __restrict__ W,
    const float* __restrict__ att,
    _Float16* __restrict__ h, float* __restrict__ es, float* __restrict__ ed) {
    if (blockIdx.y < 4) {
        gemm_body16<128>(blockIdx.x, blockIdx.y, threadIdx.x, x, W, att, h, es, ed);
        return;
    }
    int bb = blockIdx.x;
    __shared__ int hist[NBKT];
    int t = threadIdx.x;
    if (t < NBKT) hist[t] = 0;
    __syncthreads();
    int base = bb * EPB;
#pragma unroll
    for (int k = 0; k < EPB / 256; k++) {
        int e = base + k * 256 + t;
        if (e < N_EDGES) atomicAdd(&hist[dst[e] >> 8], 1);
    }
    __syncthreads();
    if (t < NBKT) offs[t * GB1 + bb] = hist[t];
}

__global__ __launch_bounds__(256) void scanB1_kernel(int* __restrict__ offs,
                                                     int* __restrict__ part2) {
    __shared__ int wsum[4];
    int t = threadIdx.x, lane = t & 63, wv = t >> 6;
    int i = blockIdx.x * 256 + t;
    int v = (i < SCAN_M) ? offs[i] : 0;
    int inc = wave_incl_scan(v, lane);
    if (lane == 63) wsum[wv] = inc;
    __syncthreads();
    if (t == 0) {
        int a = 0;
        for (int k = 0; k < 4; k++) { int x = wsum[k]; wsum[k] = a; a += x; }
    }
    __syncthreads();
    int excl = wsum[wv] + inc - v;
    if (i < SCAN_M) offs[i] = excl;
    if (t == 255) part2[blockIdx.x] = wsum[wv] + inc;
}

// scanB2 folded into consumers: each block exclusive-scans part2 (151 ints) in LDS.
__global__ __launch_bounds__(256) void scatC_kernel(const int* __restrict__ src,
                                                    const int* __restrict__ dst,
                                                    const int* __restrict__ offs,
                                                    const int* __restrict__ part2,
                                                    unsigned* __restrict__ ebuf) {
    __shared__ int cur[NBKT];
    __shared__ int base_s[NBKT];
    __shared__ int p2s[256];
    __shared__ int p2w[4];
    int t = threadIdx.x, lane = t & 63, wv = t >> 6;
    int v = (t < NB2) ? part2[t] : 0;
    int inc = wave_incl_scan(v, lane);
    if (lane == 63) p2w[wv] = inc;
    __syncthreads();
    if (t == 0) {
        int a = 0;
        for (int k = 0; k < 4; k++) { int x = p2w[k]; p2w[k] = a; a += x; }
    }
    __syncthreads();
    p2s[t] = p2w[wv] + inc - v;
    if (t < NBKT) cur[t] = 0;
    __syncthreads();
    if (t < NBKT) {
        int f = t * GB1 + blockIdx.x;
        base_s[t] = offs[f] + p2s[f >> 8];
    }
    __syncthreads();
    int base = blockIdx.x * EPB;
#pragma unroll
    for (int k = 0; k < EPB / 256; k++) {
        int e = base + k * 256 + t;
        if (e < N_EDGES) {
            int d = dst[e];
            int b = d >> 8;
            int r = atomicAdd(&cur[b], 1);
            ebuf[base_s[b] + r] = (unsigned)src[e] | ((unsigned)(d & 255) << 16);
        }
    }
}

__global__ __launch_bounds__(512) void csrD_kernel(const int* __restrict__ offs,
                                                   const int* __restrict__ part2,
                                                   const unsigned* __restrict__ ebuf,
                                                   int* __restrict__ rowptr,
                                                   unsigned short* __restrict__ csr) {
    __shared__ unsigned eb[DCAP];
    __shared__ int hist[SEGB];
    __shared__ int wsum[8];
    __shared__ int p2s[512];
    int b = blockIdx.x, t = threadIdx.x;
    int lane = t & 63, wv = t >> 6;
    {   // in-block exclusive scan of part2 (replaces scanB2 dispatch)
        int v = (t < NB2) ? part2[t] : 0;
        int inc = wave_incl_scan(v, lane);
        if (lane == 63) wsum[wv] = inc;
        __syncthreads();
        if (t == 0) {
            int a = 0;
            for (int k = 0; k < 8; k++) { int x = wsum[k]; wsum[k] = a; a += x; }
        }
        __syncthreads();
        p2s[t] = wsum[wv] + inc - v;
        __syncthreads();
    }
    int f0 = b * GB1;
    int base = offs[f0] + p2s[f0 >> 8];
    int nxt;
    if (b == NBKT - 1) nxt = N_EDGES;
    else { int f1 = (b + 1) * GB1; nxt = offs[f1] + p2s[f1 >> 8]; }
    int nb = nxt - base;
    if (nb > DCAP) nb = DCAP;  // statistically impossible; guards LDS OOB
    for (int i = t; i < SEGB; i += 512) hist[i] = 0;
    __syncthreads();
    for (int i = t; i < nb; i += 512) {
        unsigned v = ebuf[base + i];
        eb[i] = v;
        int bin = (int)((v >> 16) << 3) | (int)((v & 0xFFFFu) >> 13);
        atomicAdd(&hist[bin], 1);
    }
    __syncthreads();
    int b0 = t << 2;
    int loc0 = hist[b0], loc1 = hist[b0 + 1], loc2 = hist[b0 + 2], loc3 = hist[b0 + 3];
    int s = loc0 + loc1 + loc2 + loc3;
    int inc = wave_incl_scan(s, lane);
    if (lane == 63) wsum[wv] = inc;
    __syncthreads();
    if (t == 0) {
        int a = 0;
        for (int k = 0; k < 8; k++) { int x = wsum[k]; wsum[k] = a; a += x; }
    }
    __syncthreads();
    int run = wsum[wv] + inc - s;
    hist[b0] = run; run += loc0;
    hist[b0 + 1] = run; run += loc1;
    hist[b0 + 2] = run; run += loc2;
    hist[b0 + 3] = run;
    __syncthreads();
    if (t < 256) {
        int node = b * 256 + t;
        if (node < N_NODES) rowptr[node] = base + hist[t << 3];
    }
    if (b == 0 && t == 0) rowptr[N_NODES] = N_EDGES;
    __syncthreads();
    for (int i = t; i < nb; i += 512) {
        unsigned v = eb[i];
        int bin = (int)((v >> 16) << 3) | (int)((v & 0xFFFFu) >> 13);
        int r = atomicAdd(&hist[bin], 1);
        csr[base + r] = (unsigned short)(v & 0xFFFFu);
    }
}

// ---------------------------------------------- fused f16*f32+f32 accumulate
// v_fma_mix_f32: D.f32 = f16(half of S0) * S1.f32 + S2.f32 -- replaces the
// cvt_f32_f16 + fma pair (bitwise-identical arithmetic, half the VALU ops).
// NOTE (r7/r8 compile fails): asm operands must be plain scalar locals, and
// macro parameter must NOT be named `w` (token-substitutes into `.w`!).
__device__ __forceinline__ void fmamix2(float& alo, float& ahi, unsigned dw,
                                        float wgt) {
    asm("v_fma_mix_f32 %0, %2, %3, %0 op_sel_hi:[1,0,0]"
        : "=v"(alo) : "0"(alo), "v"(dw), "v"(wgt));
    asm("v_fma_mix_f32 %0, %2, %3, %0 op_sel:[1,0,0] op_sel_hi:[1,0,0]"
        : "=v"(ahi) : "0"(ahi), "v"(dw), "v"(wgt));
}

#define EDGE_ACC(hv, wgt) do {                                               \
    unsigned _d0 = (hv).x, _d1 = (hv).y, _d2 = (hv).z, _d3 = (hv).w;         \
    float _w = (wgt);                                                        \
    fmamix2(acc[0], acc[1], _d0, _w);                                        \
    fmamix2(acc[2], acc[3], _d1, _w);                                        \
    fmamix2(acc[4], acc[5], _d2, _w);                                        \
    fmamix2(acc[6], acc[7], _d3, _w);                                        \
} while (0)

// ---------------------------------------------- agg loop (shared by both kernels)
// SPLIT-WAVE: each HALF-WAVE (32 lanes = 4 edge slots x 8 heads) owns one
// node with its OWN exact trip count. Proven round-5 structure; inner
// accumulate via v_fma_mix (64 -> 32 VALU ops per 16-edge batch).
// KNOWN-GOOD round-9 loop. Both deeper-MLP variants measured WORSE:
// 32-edge hoist (+64 VGPR) = occupancy cliff, -11 us; csr-prefetch =
// unexplained absmax blowup. Agg is at its gather floor (~205 MB line
// traffic/dispatch, FETCH ~85-100 MB at ~2.3 TB/s effective).
#define AGG_LOOP()                                                          \
    int beg = rowptr[n], end = rowptr[n + 1];                               \
    float edn = ed_in[n * NH + o];                                          \
    int last = (end > beg) ? (end - 1) : 0;                                 \
    float acc[8] = {0.f, 0.f, 0.f, 0.f, 0.f, 0.f, 0.f, 0.f};                \
    float ssum = 0.f;                                                       \
    int j = beg;                                                            \
    for (; j + 16 <= end; j += 16) {                                        \
        int s0 = csr[j + g];                                                \
        int s1 = csr[j + 4 + g];                                            \
        int s2 = csr[j + 8 + g];                                            \
        int s3 = csr[j + 12 + g];                                           \
        uint4 hv0 = h8[s0 * 8 + o];                                         \
        uint4 hv1 = h8[s1 * 8 + o];                                         \
        uint4 hv2 = h8[s2 * 8 + o];                                         \
        uint4 hv3 = h8[s3 * 8 + o];                                         \
        float ev0 = es_in[s0 * NH + o];                                     \
        float ev1 = es_in[s1 * NH + o];                                     \
        float ev2 = es_in[s2 * NH + o];                                     \
        float ev3 = es_in[s3 * NH + o];                                     \
        float e0 = ev0 + edn; e0 = (e0 > 0.f) ? e0 : 0.2f * e0;             \
        float e1 = ev1 + edn; e1 = (e1 > 0.f) ? e1 : 0.2f * e1;             \
        float e2 = ev2 + edn; e2 = (e2 > 0.f) ? e2 : 0.2f * e2;             \
        float e3 = ev3 + edn; e3 = (e3 > 0.f) ? e3 : 0.2f * e3;             \
        float w0 = __expf(e0), w1 = __expf(e1);                             \
        float w2 = __expf(e2), w3 = __expf(e3);                             \
        EDGE_ACC(hv0, w0);                                                  \
        EDGE_ACC(hv1, w1);                                                  \
        EDGE_ACC(hv2, w2);                                                  \
        EDGE_ACC(hv3, w3);                                                  \
        ssum += w0 + w1;                                                    \
        ssum += w2 + w3;                                                    \
    }                                                                       \
    if (j < end) {                                                          \
        int i0 = j + g, i1 = j + 4 + g, i2 = j + 8 + g, i3 = j + 12 + g;    \
        int s0 = csr[(i0 < end) ? i0 : last];                               \
        int s1 = csr[(i1 < end) ? i1 : last];                               \
        int s2 = csr[(i2 < end) ? i2 : last];                               \
        int s3 = csr[(i3 < end) ? i3 : last];                               \
        uint4 hv0 = h8[s0 * 8 + o];                                         \
        uint4 hv1 = h8[s1 * 8 + o];                                         \
        uint4 hv2 = h8[s2 * 8 + o];                                         \
        uint4 hv3 = h8[s3 * 8 + o];                                         \
        float ev0 = es_in[s0 * NH + o];                                     \
        float ev1 = es_in[s1 * NH + o];                                     \
        float ev2 = es_in[s2 * NH + o];                                     \
        float ev3 = es_in[s3 * NH + o];                                     \
        float e0 = ev0 + edn; e0 = (e0 > 0.f) ? e0 : 0.2f * e0;             \
        float e1 = ev1 + edn; e1 = (e1 > 0.f) ? e1 : 0.2f * e1;             \
        float e2 = ev2 + edn; e2 = (e2 > 0.f) ? e2 : 0.2f * e2;             \
        float e3 = ev3 + edn; e3 = (e3 > 0.f) ? e3 : 0.2f * e3;             \
        float w0 = (i0 < end) ? __expf(e0) : 0.f;                           \
        float w1 = (i1 < end) ? __expf(e1) : 0.f;                           \
        float w2 = (i2 < end) ? __expf(e2) : 0.f;                           \
        float w3 = (i3 < end) ? __expf(e3) : 0.f;                           \
        EDGE_ACC(hv0, w0);                                                  \
        EDGE_ACC(hv1, w1);                                                  \
        EDGE_ACC(hv2, w2);                                                  \
        EDGE_ACC(hv3, w3);                                                  \
        ssum += w0 + w1;                                                    \
        ssum += w2 + w3;                                                    \
    }                                                                       \
    _Pragma("unroll")                                                       \
    for (int i = 0; i < 8; i++) {                                           \
        acc[i] += __shfl_xor(acc[i], 8);                                    \
        acc[i] += __shfl_xor(acc[i], 16);                                   \
    }                                                                       \
    ssum += __shfl_xor(ssum, 8);                                            \
    ssum += __shfl_xor(ssum, 16);

// ------------------------------------------------------------- aggregation
// Final layer: plain agg -> d_out, no ELU.
__global__ __launch_bounds__(256) void agg_kernel(
    const uint4* __restrict__ h8, const float* __restrict__ es_in,
    const float* __restrict__ ed_in, const int* __restrict__ rowptr,
    const unsigned short* __restrict__ csr, const float4* __restrict__ b4,
    float4* __restrict__ out4, int apply_elu) {
    int t = threadIdx.x;
    int wv = t >> 6, L = t & 63;
    int n = blockIdx.x * 8 + wv * 2 + (L >> 5);
    int g = (L >> 3) & 3, o = L & 7;
    AGG_LOOP()

    if (g == 0) {
        float inv = 1.f / (ssum + 1e-16f);
        float4 bv0 = b4[2 * o], bv1 = b4[2 * o + 1];
        float4 r0, r1;
        r0.x = acc[0] * inv + bv0.x; r0.y = acc[1] * inv + bv0.y;
        r0.z = acc[2] * inv + bv0.z; r0.w = acc[3] * inv + bv0.w;
        r1.x = acc[4] * inv + bv1.x; r1.y = acc[5] * inv + bv1.y;
        r1.z = acc[6] * inv + bv1.z; r1.w = acc[7] * inv + bv1.w;
        if (apply_elu) {
            r0.x = (r0.x > 0.f) ? r0.x : (__expf(r0.x) - 1.f);
            r0.y = (r0.y > 0.f) ? r0.y : (__expf(r0.y) - 1.f);
            r0.z = (r0.z > 0.f) ? r0.z : (__expf(r0.z) - 1.f);
            r0.w = (r0.w > 0.f) ? r0.w : (__expf(r0.w) - 1.f);
            r1.x = (r1.x > 0.f) ? r1.x : (__expf(r1.x) - 1.f);
            r1.y = (r1.y > 0.f) ? r1.y : (__expf(r1.y) - 1.f);
            r1.z = (r1.z > 0.f) ? r1.z : (__expf(r1.z) - 1.f);
            r1.w = (r1.w > 0.f) ? r1.w : (__expf(r1.w) - 1.f);
        }
        out4[n * 16 + 2 * o] = r0;
        out4[n * 16 + 2 * o + 1] = r1;
    }
}

// ----------------------------------------- aggregation + NEXT-LAYER GEMM fused
// Layers 0-2: agg output row (bias+ELU) is NODE-LOCAL input to the next
// layer's GEMM -> keep it in LDS, run the 64x64 GEMM as an epilogue in the
// same half-wave (lane = 2 features), write h/es/ed for the next layer.
// W_next staged per block in pair-interleaved LDS layout wTp[li*132+k*2+c]
// = W[k][2*li+c] (stride 132 floats: 16B-aligned b128 rows, <=4-way banks).
__global__ __launch_bounds__(256) void aggemm_kernel(
    const uint4* __restrict__ h8, const float* __restrict__ es_in,
    const float* __restrict__ ed_in, const int* __restrict__ rowptr,
    const unsigned short* __restrict__ csr, const float4* __restrict__ b4,
    const float* __restrict__ Wn, const float* __restrict__ attn,
    _Float16* __restrict__ h_out, float* __restrict__ es_out,
    float* __restrict__ ed_out) {
    __shared__ alignas(16) float wTp[32 * 132];
    __shared__ alignas(16) float outs[8][64];
    int t = threadIdx.x;
    {   // stage W_next (16 KB) -> LDS; issues early, covered by agg latency
        const float4* W4 = (const float4*)Wn;
#pragma unroll
        for (int q = 0; q < 4; q++) {
            int idx4 = q * 256 + t;      // 1024 float4 = 4096 floats
            float4 wv4 = W4[idx4];
            int base = idx4 << 2;
            int k = base >> 6, fb = base & 63;   // fb multiple of 4
            float2* p0 = (float2*)&wTp[(fb >> 1) * 132 + k * 2];
            float2* p1 = (float2*)&wTp[((fb >> 1) + 1) * 132 + k * 2];
            p0->x = wv4.x; p0->y = wv4.y;
            p1->x = wv4.z; p1->y = wv4.w;
        }
    }
    int wv = t >> 6, L = t & 63;
    int slot = wv * 2 + (L >> 5);
    int n = blockIdx.x * 8 + slot;
    int g = (L >> 3) & 3, o = L & 7;
    AGG_LOOP()

    if (g == 0) {   // bias + ELU (always: intermediate layers), row -> LDS
        float inv = 1.f / (ssum + 1e-16f);
        float4 bv0 = b4[2 * o], bv1 = b4[2 * o + 1];
        float4 r0, r1;
        r0.x = acc[0] * inv + bv0.x; r0.y = acc[1] * inv + bv0.y;
        r0.z = acc[2] * inv + bv0.z; r0.w = acc[3] * inv + bv0.w;
        r1.x = acc[4] * inv + bv1.x; r1.y = acc[5] * inv + bv1.y;
        r1.z = acc[6] * inv + bv1.z; r1.w = acc[7] * inv + bv1.w;
        r0.x = (r0.x > 0.f) ? r0.x : (__expf(r0.x) - 1.f);
        r0.y = (r0.y > 0.f) ? r0.y : (__expf(r0.y) - 1.f);
        r0.z = (r0.z > 0.f) ? r0.z : (__expf(r0.z) - 1.f);
        r0.w = (r0.w > 0.f) ? r0.w : (__expf(r0.w) - 1.f);
        r1.x = (r1.x > 0.f) ? r1.x : (__expf(r1.x) - 1.f);
        r1.y = (r1.y > 0.f) ? r1.y : (__expf(r1.y) - 1.f);
        r1.z = (r1.z > 0.f) ? r1.z : (__expf(r1.z) - 1.f);
        r1.w = (r1.w > 0.f) ? r1.w : (__expf(r1.w) - 1.f);
        float4* os = (float4*)&outs[slot][0];
        os[2 * o] = r0;
        os[2 * o + 1] = r1;
    }
    __syncthreads();

    // epilogue GEMM: lane covers features f0, f0+1 of the next layer
    int li = L & 31;
    int f0 = li << 1;
    const float* wrow = &wTp[li * 132];
    float h0 = 0.f, h1 = 0.f;
#pragma unroll
    for (int k4 = 0; k4 < 64; k4 += 4) {
        float4 ov = *(const float4*)&outs[slot][k4];       // broadcast/half
        float4 wa = *(const float4*)&wrow[k4 * 2];         // k4,k4+1 pairs
        float4 wb = *(const float4*)&wrow[k4 * 2 + 4];     // k4+2,k4+3 pairs
        h0 += ov.x * wa.x + ov.y * wa.z + ov.z * wb.x + ov.w * wb.z;
        h1 += ov.x * wa.y + ov.y * wa.w + ov.z * wb.y + ov.w * wb.w;
    }
    // attention logits for next layer (4-lane tree per head)
    float sa = h0 * attn[f0] + h1 * attn[f0 + 1];
    float da = h0 * attn[64 + f0] + h1 * attn[64 + f0 + 1];
    sa += __shfl_xor(sa, 1); sa += __shfl_xor(sa, 2);
    da += __shfl_xor(da, 1); da += __shfl_xor(da, 2);
    if ((li & 3) == 0) {
        int hh = li >> 2;
        es_out[n * NH + hh] = sa;
        ed_out[n * NH + hh] = da;
    }
    union { _Float16 hf[2]; unsigned u; } cv;
    cv.hf[0] = (_Float16)h0;
    cv.hf[1] = (_Float16)h1;
    *(unsigned*)(h_out + (size_t)n * HD + f0) = cv.u;
}

// ---------------------------------------------------------------- launcher
extern "C" void kernel_launch(void* const* d_in, const int* in_sizes, int n_in,
                              void* d_out, int out_size, void* d_ws, size_t ws_size,
                              hipStream_t stream) {
    const float* x   = (const float*)d_in[0];
    const int*   ei  = (const int*)d_in[1];
    const int*   src = ei;
    const int*   dst = ei + N_EDGES;
    const float* W[4]   = {(const float*)d_in[2], (const float*)d_in[5],
                           (const float*)d_in[8], (const float*)d_in[11]};
    const float* att[4] = {(const float*)d_in[3], (const float*)d_in[6],
                           (const float*)d_in[9], (const float*)d_in[12]};
    const float* bb[4]  = {(const float*)d_in[4], (const float*)d_in[7],
                           (const float*)d_in[10], (const float*)d_in[13]};

    char* wsb = (char*)d_ws;
    size_t off = 0;
    auto alloc = [&](size_t bytes) -> void* {
        size_t a = (off + 255) & ~(size_t)255;
        off = a + bytes;
        return (void*)(wsb + a);
    };
    int*            offs   = (int*)alloc((size_t)SCAN_M * 4);
    int*            part2  = (int*)alloc((size_t)NB2 * 4);
    unsigned*       ebuf   = (unsigned*)alloc((size_t)N_EDGES * 4);
    int*            rowptr = (int*)alloc((size_t)(N_NODES + 1) * 4);
    unsigned short* csr    = (unsigned short*)alloc((size_t)N_EDGES * 2);
    _Float16*       h_a    = (_Float16*)alloc((size_t)N_NODES * HD * 2);
    float*          es_a   = (float*)alloc((size_t)N_NODES * NH * 4);
    float*          ed_a   = (float*)alloc((size_t)N_NODES * NH * 4);
    _Float16*       h_b    = (_Float16*)alloc((size_t)N_NODES * HD * 2);
    float*          es_b   = (float*)alloc((size_t)N_NODES * NH * 4);
    float*          ed_b   = (float*)alloc((size_t)N_NODES * NH * 4);

    const int GA = N_NODES / 8;  // 6250 blocks, 8 nodes per block
    const dim3 GF(GBN, 5);       // y<4: gemm layer0, y==4: histA

    // CSR build + layer-0 GEMM fused (independent work overlapped)
    histA_gemm_kernel<<<GF, 256, 0, stream>>>(dst, offs, x, W[0], att[0],
                                              h_a, es_a, ed_a);
    scanB1_kernel<<<NB2, 256, 0, stream>>>(offs, part2);
    scatC_kernel<<<GB1, 256, 0, stream>>>(src, dst, offs, part2, ebuf);
    csrD_kernel<<<NBKT, 512, 0, stream>>>(offs, part2, ebuf, rowptr, csr);

    // layers 0-2: agg + fused next-layer GEMM (double-buffered h/es/ed)
    aggemm_kernel<<<GA, 256, 0, stream>>>((const uint4*)h_a, es_a, ed_a,
                                          rowptr, csr, (const float4*)bb[0],
                                          W[1], att[1], h_b, es_b, ed_b);
    aggemm_kernel<<<GA, 256, 0, stream>>>((const uint4*)h_b, es_b, ed_b,
                                          rowptr, csr, (const float4*)bb[1],
                                          W[2], att[2], h_a, es_a, ed_a);
    aggemm_kernel<<<GA, 256, 0, stream>>>((const uint4*)h_a, es_a, ed_a,
                                          rowptr, csr, (const float4*)bb[2],
                                          W[3], att[3], h_b, es_b, ed_b);
    // final layer: plain agg -> d_out (no ELU)
    agg_kernel<<<GA, 256, 0, stream>>>((const uint4*)h_b, es_b, ed_b,
                                       rowptr, csr, (const float4*)bb[3],
                                       (float4*)d_out, 0);
}